// Round 6
// baseline (1528.289 us; speedup 1.0000x reference)
//
#include <hip/hip_runtime.h>
#include <cstddef>
#include <cstdint>

#define Tn 512
#define Bn 512

typedef float f32x2 __attribute__((ext_vector_type(2)));

__device__ __forceinline__ float rlane(float v, int lane) {
    return __uint_as_float((unsigned)__builtin_amdgcn_readlane((int)__float_as_uint(v), lane));
}
__device__ __forceinline__ float sigm(float x) { return 1.0f / (1.0f + __expf(-x)); }
// tanh(x) = 1 - 2/(1+e^{2x}); inf-safe at both ends
__device__ __forceinline__ float tanhf_(float x) { return 1.0f - 2.0f / (1.0f + __expf(2.0f * x)); }

// LDS-visibility barrier WITHOUT the __syncthreads vmcnt(0) drain.
#define BAR_LGKM() asm volatile("s_waitcnt lgkmcnt(0)\n\ts_barrier" ::: "memory")
// Pin a value into arch-VGPR class.
#define PIN(v) asm volatile("" : "+v"(v))

#define ACT(GI, GF, GG, GO, C, H)                              \
    do {                                                       \
        C = sigm(GF) * (C) + sigm(GI) * tanhf_(GG);            \
        H = sigm(GO) * tanhf_(C);                              \
    } while (0)

// K-window [OFF,OFF+N) of source SA, crossing into SB at SPLIT (lane OFF+kk-64).
// All rlane indices are literals after unroll; pk-FMA via float2 gate pairs.
#define BODYN(N, SA, SB, OFF, SPLIT)                                    \
    _Pragma("unroll")                                                   \
    for (int kk = 0; kk < (N); ++kk) {                                  \
        const float v = (kk < (SPLIT)) ? rlane((SA), (OFF) + kk)        \
                                       : rlane((SB), (OFF) + kk - 64);  \
        const f32x2 v2 = {v, v};                                        \
        a01 = __builtin_elementwise_fma(v2, wp01[kk], a01);             \
        a23 = __builtin_elementwise_fma(v2, wp23[kk], a23);             \
    }

// ---------------------------------------------------------------------------
// Layer 0 (IN=1), both directions of ONE batch element per 512-thr block.
// wv = dir*4 + q; wave q owns h-K window [16q,16q+16): weights = 16 x f32x2
// pairs x 2 = 64 VGPRs -> live set ~95 under the 128 budget of (512,4)
// [4 waves/SIMD, 2 blocks/CU, 512 blocks all-resident].
// Per step: producers do 16 readlane + 32 pk_fma -> partial (b128, dbuf) ->
// BAR1 -> wave q==3 of each dir reduces 4 partials + x-term + activation,
// writes h to LDS + h0out -> BAR2 -> producers re-load h (b32, 2/bank free).
// ---------------------------------------------------------------------------
__global__ __launch_bounds__(512, 4) void k_lstm_l0(
    const float* __restrict__ x,
    const float* __restrict__ wih_f, const float* __restrict__ whh_f,
    const float* __restrict__ bih_f, const float* __restrict__ bhh_f,
    const float* __restrict__ wih_r, const float* __restrict__ whh_r,
    const float* __restrict__ bih_r, const float* __restrict__ bhh_r,
    float* __restrict__ h0out)
{
    const int tid = threadIdx.x;
    const int wv  = tid >> 6;        // 0..7
    const int j   = tid & 63;
    const int dir = wv >> 2;
    const int q   = wv & 3;          // K quarter
    const int b   = blockIdx.x;
    const int klo = q * 16;

    const float* __restrict__ wih = dir ? wih_r : wih_f;
    const float* __restrict__ whh = dir ? whh_r : whh_f;
    const float* __restrict__ bih = dir ? bih_r : bih_f;
    const float* __restrict__ bhh = dir ? bhh_r : bhh_f;

    __shared__ float  xs[Tn];               // 2 KB
    __shared__ float4 part[2][8][64];       // 16 KB  [buf][wv][unit]
    __shared__ float  h_lds[2][2][64];      // 1 KB   [buf][dir][unit]

    xs[tid] = x[(size_t)b * Tn + tid];

    f32x2 wp01[16], wp23[16];
    #pragma unroll
    for (int kk = 0; kk < 16; ++kk) {
        const int k = klo + kk;
        wp01[kk] = (f32x2){whh[(size_t)(0 * 64 + j) * 64 + k], whh[(size_t)(1 * 64 + j) * 64 + k]};
        wp23[kk] = (f32x2){whh[(size_t)(2 * 64 + j) * 64 + k], whh[(size_t)(3 * 64 + j) * 64 + k]};
        PIN(wp01[kk]); PIN(wp23[kk]);
    }
    float wx[4], bias[4];
    #pragma unroll
    for (int g = 0; g < 4; ++g) {
        wx[g]   = wih[g * 64 + j];
        bias[g] = bih[g * 64 + j] + bhh[g * 64 + j];
    }
    __syncthreads();   // once: xs visible

    float h_src = 0.0f, h = 0.0f, c = 0.0f;
    float* __restrict__ outp = h0out + (size_t)b * Tn * 128 + dir * 64 + j;

    for (int s = 0; s < Tn; ++s) {
        const int t  = dir ? (Tn - 1 - s) : s;
        const int bf = s & 1;

        f32x2 a01 = {0.0f, 0.0f}, a23 = {0.0f, 0.0f};
        switch (q) {   // wave-uniform; literal readlane bases
            case 0:  BODYN(16, h_src, h_src,  0, 16); break;
            case 1:  BODYN(16, h_src, h_src, 16, 16); break;
            case 2:  BODYN(16, h_src, h_src, 32, 16); break;
            default: BODYN(16, h_src, h_src, 48, 16); break;
        }
        part[bf][wv][j] = make_float4(a01.x, a01.y, a23.x, a23.y);
        BAR_LGKM();                       // BAR1: partials visible
        if (q == 3) {                     // reducer for this dir
            const float4 q0 = part[bf][dir * 4 + 0][j];
            const float4 q1 = part[bf][dir * 4 + 1][j];
            const float4 q2 = part[bf][dir * 4 + 2][j];
            const float4 q3 = part[bf][dir * 4 + 3][j];
            const float xt = xs[t];
            const float gi = fmaf(xt, wx[0], bias[0]) + q0.x + q1.x + q2.x + q3.x;
            const float gf = fmaf(xt, wx[1], bias[1]) + q0.y + q1.y + q2.y + q3.y;
            const float gg = fmaf(xt, wx[2], bias[2]) + q0.z + q1.z + q2.z + q3.z;
            const float go = fmaf(xt, wx[3], bias[3]) + q0.w + q1.w + q2.w + q3.w;
            ACT(gi, gf, gg, go, c, h);
            h_lds[bf][dir][j] = h;
            outp[(size_t)t * 128] = h;    // store floats across barriers (no drain)
        }
        BAR_LGKM();                       // BAR2: h visible
        if (q == 3) h_src = h;
        else        h_src = h_lds[bf][dir][j];
    }
}

// ---------------------------------------------------------------------------
// Layer 1 forward scan, fused input GEMM (K = 128 x + 64 h = 192). One batch
// element per 512-thr block, K split 24/wave over 8 waves -> 24 f32x2 pairs
// x 2 = 96 weight VGPRs; live set ~120 under the 128 budget of (512,4)
// [4 waves/SIMD, 2 blocks/CU, 512 blocks all-resident].
// K windows: w0 xa[0:24) w1 xa[24:48) w2 xa[48:64)+xb[0:8) w3 xb[8:32)
//            w4 xb[32:56) w5 xb[56:64)+h[0:16) w6 h[16:40) w7 h[40:64)
// x sources are 2-step-deep register-prefetched (lgkm-only barriers never
// drain vmcnt). Wave 7 is the sole reducer (8 partials + bias + activation),
// broadcasting h through a 256 B LDS hop; waves 5,6 re-load it (b32, free).
// ---------------------------------------------------------------------------
__global__ __launch_bounds__(512, 4) void k_lstm_l1f(
    const float* __restrict__ h0in,
    const float* __restrict__ wih, const float* __restrict__ whh,
    const float* __restrict__ bih, const float* __restrict__ bhh,
    float* __restrict__ h1last)
{
    const int tid = threadIdx.x;
    const int wv  = tid >> 6;        // 0..7
    const int j   = tid & 63;
    const int b   = blockIdx.x;
    const int kbase = wv * 24;

    __shared__ float4 part[2][8][64];   // 16 KB
    __shared__ float  h_lds[2][64];     // 512 B

    f32x2 wp01[24], wp23[24];
    #pragma unroll
    for (int kk = 0; kk < 24; ++kk) {
        const int k = kbase + kk;
        const float v0 = (k < 128) ? wih[(size_t)(0 * 64 + j) * 128 + k] : whh[(size_t)(0 * 64 + j) * 64 + k - 128];
        const float v1 = (k < 128) ? wih[(size_t)(1 * 64 + j) * 128 + k] : whh[(size_t)(1 * 64 + j) * 64 + k - 128];
        const float v2 = (k < 128) ? wih[(size_t)(2 * 64 + j) * 128 + k] : whh[(size_t)(2 * 64 + j) * 64 + k - 128];
        const float v3 = (k < 128) ? wih[(size_t)(3 * 64 + j) * 128 + k] : whh[(size_t)(3 * 64 + j) * 64 + k - 128];
        wp01[kk] = (f32x2){v0, v1};
        wp23[kk] = (f32x2){v2, v3};
        PIN(wp01[kk]); PIN(wp23[kk]);
    }
    float bias[4];
    #pragma unroll
    for (int g = 0; g < 4; ++g) bias[g] = bih[g * 64 + j] + bhh[g * 64 + j];

    const float* __restrict__ xrow = h0in + (size_t)b * Tn * 128;
    const bool needA = (wv <= 2);
    const bool needB = (wv >= 2 && wv <= 5);
    // 2-deep rotating prefetch: src = x(t), p1 = x(t+1), p2 issued for t+2
    float srcA = 0.0f, pA1 = 0.0f, srcB = 0.0f, pB1 = 0.0f;
    if (needA) { srcA = xrow[j];      pA1 = xrow[128 + j]; }
    if (needB) { srcB = xrow[64 + j]; pB1 = xrow[128 + 64 + j]; }
    float h_src = 0.0f, h = 0.0f, c = 0.0f;

    for (int t = 0; t < Tn; ++t) {
        const int bf = t & 1;
        const int tp = (t + 2 < Tn) ? t + 2 : Tn - 1;
        float pA2 = 0.0f, pB2 = 0.0f;
        if (needA) pA2 = xrow[(size_t)tp * 128 + j];
        if (needB) pB2 = xrow[(size_t)tp * 128 + 64 + j];

        f32x2 a01 = {0.0f, 0.0f}, a23 = {0.0f, 0.0f};
        switch (wv) {   // wave-uniform; literal readlane indices
            case 0:  BODYN(24, srcA, srcA,   0, 24); break;
            case 1:  BODYN(24, srcA, srcA,  24, 24); break;
            case 2:  BODYN(24, srcA, srcB,  48, 16); break;   // xb lanes 0..7
            case 3:  BODYN(24, srcB, srcB,   8, 24); break;
            case 4:  BODYN(24, srcB, srcB,  32, 24); break;
            case 5:  BODYN(24, srcB, h_src, 56,  8); break;   // h lanes 0..15
            case 6:  BODYN(24, h_src, h_src, 16, 24); break;
            default: BODYN(24, h_src, h_src, 40, 24); break;
        }
        part[bf][wv][j] = make_float4(a01.x, a01.y, a23.x, a23.y);
        BAR_LGKM();                       // BAR1: partials visible
        if (wv == 7) {                    // sole reducer
            const float4 q0 = part[bf][0][j];
            const float4 q1 = part[bf][1][j];
            const float4 q2 = part[bf][2][j];
            const float4 q3 = part[bf][3][j];
            const float4 q4 = part[bf][4][j];
            const float4 q5 = part[bf][5][j];
            const float4 q6 = part[bf][6][j];
            const float4 q7 = part[bf][7][j];
            const float gi = bias[0] + q0.x + q1.x + q2.x + q3.x + q4.x + q5.x + q6.x + q7.x;
            const float gf = bias[1] + q0.y + q1.y + q2.y + q3.y + q4.y + q5.y + q6.y + q7.y;
            const float gg = bias[2] + q0.z + q1.z + q2.z + q3.z + q4.z + q5.z + q6.z + q7.z;
            const float go = bias[3] + q0.w + q1.w + q2.w + q3.w + q4.w + q5.w + q6.w + q7.w;
            ACT(gi, gf, gg, go, c, h);
            h_lds[bf][j] = h;
        }
        BAR_LGKM();                       // BAR2: h visible
        if (wv == 7)                 h_src = h;
        else if (wv == 5 || wv == 6) h_src = h_lds[bf][j];
        srcA = pA1; pA1 = pA2;
        srcB = pB1; pB1 = pB2;
    }
    if (wv == 7) h1last[(size_t)b * 64 + j] = h;
}

// ---------------------------------------------------------------------------
// Layer-1 backward direction collapses to ONE step at t=T-1 (zero init state),
// then the final FC. One wave per batch element.
// ---------------------------------------------------------------------------
__global__ __launch_bounds__(64, 1) void k_l1r_fc(
    const float* __restrict__ h0in,
    const float* __restrict__ wihr,
    const float* __restrict__ bihr, const float* __restrict__ bhhr,
    const float* __restrict__ h1last,
    const float* __restrict__ fcw, const float* __restrict__ fcb,
    float* __restrict__ out)
{
    const int b = blockIdx.x;
    const int j = threadIdx.x;
    const float* __restrict__ xrow = h0in + ((size_t)b * Tn + (Tn - 1)) * 128;
    const float x1a = xrow[j];
    const float x1b = xrow[64 + j];
    float acc[4];
    #pragma unroll
    for (int g = 0; g < 4; ++g) {
        const int r = g * 64 + j;
        float a = bihr[r] + bhhr[r];
        const float* __restrict__ wr = wihr + (size_t)r * 128;
        #pragma unroll
        for (int d4 = 0; d4 < 16; ++d4) {
            const float4 w4 = *reinterpret_cast<const float4*>(&wr[d4 * 4]);
            a = fmaf(rlane(x1a, d4 * 4 + 0), w4.x, a);
            a = fmaf(rlane(x1a, d4 * 4 + 1), w4.y, a);
            a = fmaf(rlane(x1a, d4 * 4 + 2), w4.z, a);
            a = fmaf(rlane(x1a, d4 * 4 + 3), w4.w, a);
        }
        #pragma unroll
        for (int d4 = 0; d4 < 16; ++d4) {
            const float4 w4 = *reinterpret_cast<const float4*>(&wr[64 + d4 * 4]);
            a = fmaf(rlane(x1b, d4 * 4 + 0), w4.x, a);
            a = fmaf(rlane(x1b, d4 * 4 + 1), w4.y, a);
            a = fmaf(rlane(x1b, d4 * 4 + 2), w4.z, a);
            a = fmaf(rlane(x1b, d4 * 4 + 3), w4.w, a);
        }
        acc[g] = a;
    }
    const float cr = sigm(acc[0]) * tanhf_(acc[2]);
    const float hr = sigm(acc[3]) * tanhf_(cr);
    float v = h1last[(size_t)b * 64 + j] * fcw[j] + hr * fcw[64 + j];
    #pragma unroll
    for (int off = 32; off > 0; off >>= 1) v += __shfl_xor(v, off, 64);
    if (j == 0) out[b] = v + fcb[0];
}

// ---------------------------------------------------------------------------
extern "C" void kernel_launch(void* const* d_in, const int* in_sizes, int n_in,
                              void* d_out, int out_size, void* d_ws, size_t ws_size,
                              hipStream_t stream)
{
    const float* x       = (const float*)d_in[0];
    const float* wih_l0  = (const float*)d_in[1];
    const float* whh_l0  = (const float*)d_in[2];
    const float* bih_l0  = (const float*)d_in[3];
    const float* bhh_l0  = (const float*)d_in[4];
    const float* wih_l0r = (const float*)d_in[5];
    const float* whh_l0r = (const float*)d_in[6];
    const float* bih_l0r = (const float*)d_in[7];
    const float* bhh_l0r = (const float*)d_in[8];
    const float* wih_l1  = (const float*)d_in[9];
    const float* whh_l1  = (const float*)d_in[10];
    const float* bih_l1  = (const float*)d_in[11];
    const float* bhh_l1  = (const float*)d_in[12];
    const float* wih_l1r = (const float*)d_in[13];
    const float* whh_l1r = (const float*)d_in[14];
    const float* bih_l1r = (const float*)d_in[15];
    const float* bhh_l1r = (const float*)d_in[16];
    const float* fcw     = (const float*)d_in[17];
    const float* fcb     = (const float*)d_in[18];
    (void)whh_l1r; (void)in_sizes; (void)n_in; (void)out_size;

    // ws layout: h0 [512][512][128] f32 (134.2 MB) + h1last [512][64] f32
    float* h0     = (float*)d_ws;
    float* h1last = h0 + (size_t)Bn * Tn * 128;
    (void)ws_size;

    k_lstm_l0<<<dim3(Bn), dim3(512), 0, stream>>>(
        x, wih_l0, whh_l0, bih_l0, bhh_l0,
        wih_l0r, whh_l0r, bih_l0r, bhh_l0r, h0);
    k_lstm_l1f<<<dim3(Bn), dim3(512), 0, stream>>>(
        h0, wih_l1, whh_l1, bih_l1, bhh_l1, h1last);
    k_l1r_fc<<<dim3(Bn), dim3(64), 0, stream>>>(
        h0, wih_l1r, bih_l1r, bhh_l1r, h1last, fcw, fcb, (float*)d_out);
}